// Round 1
// baseline (773.541 us; speedup 1.0000x reference)
//
#include <hip/hip_runtime.h>
#include <math.h>

#define Mdim 2048
#define FD   128
#define TM   64
#define TN   64
#define NEG  (-1e30f)

// ---------------- Kernel 1: per-row fp64 norms + fp32 inv-norms ----------------
__global__ void norms_kernel(const float* __restrict__ x,
                             double* __restrict__ nrm_d,
                             float* __restrict__ inv_f) {
    int row = blockIdx.x;          // 0 .. B*M-1
    int t = threadIdx.x;           // 0..63 (one wave)
    const float* p = x + (size_t)row * FD;
    float v0 = p[t];
    float v1 = p[t + 64];
    double d = (double)v0 * (double)v0 + (double)v1 * (double)v1;
    #pragma unroll
    for (int off = 32; off > 0; off >>= 1) d += __shfl_down(d, off);
    if (t == 0) {
        double nrm = sqrt(d);
        nrm_d[row] = nrm;
        inv_f[row] = (float)(1.0 / fmax(nrm, 1e-12));
    }
}

// sorted-desc top-4 insert (swap-chain; early-out keeps it cheap)
__device__ __forceinline__ void ins4(float v, int n, float tv[4], int ti[4]) {
    if (v <= tv[3]) return;
    #pragma unroll
    for (int s = 0; s < 4; ++s) {
        if (v > tv[s]) {
            float ov = tv[s]; int oi = ti[s];
            tv[s] = v; ti[s] = n;
            v = ov; n = oi;
        }
    }
}

// ---------------- Kernel 2: tiled fp32 GEMM + top-4 + fp64 refine + scatter ----------------
__launch_bounds__(256, 2)
__global__ void topk_kernel(const float* __restrict__ x,
                            const double* __restrict__ nrm_d,
                            const float* __restrict__ inv_f,
                            float* __restrict__ out) {
    // 64 KB LDS: A-tile [FD][TM] 32KB + B-tile [FD][TN] 32KB (regions reused later)
    __shared__ __align__(16) char smem[65536];
    float* Ald = (float*)smem;
    float* Bld = (float*)(smem + 32768);

    const int rowTiles = Mdim / TM;        // 32
    int b  = blockIdx.x / rowTiles;
    int rt = blockIdx.x % rowTiles;
    int row0 = rt * TM;
    const float* xb = x + (size_t)b * Mdim * FD;
    const double* nb = nrm_d + (size_t)b * Mdim;
    const float* ib = inv_f + (size_t)b * Mdim;

    int tid = threadIdx.x;
    int tx = tid & 15, ty = tid >> 4;

    // stage A: 64 rows x 128 k, normalized, stored transposed [k][m]
    for (int i = tid; i < TM * (FD / 4); i += 256) {
        int r  = i >> 5;            // i / 32
        int k4 = (i & 31) << 2;
        float4 v = *(const float4*)(xb + (size_t)(row0 + r) * FD + k4);
        float inv = ib[row0 + r];
        Ald[(k4 + 0) * TM + r] = v.x * inv;
        Ald[(k4 + 1) * TM + r] = v.y * inv;
        Ald[(k4 + 2) * TM + r] = v.z * inv;
        Ald[(k4 + 3) * TM + r] = v.w * inv;
    }

    float tv[4][4]; int ti[4][4];
    #pragma unroll
    for (int i = 0; i < 4; ++i)
        #pragma unroll
        for (int s = 0; s < 4; ++s) { tv[i][s] = NEG; ti[i][s] = -1; }

    for (int ch = 0; ch < Mdim / TN; ++ch) {
        int col0 = ch * TN;
        __syncthreads();   // covers A-stage on first iter, protects Bld reuse after
        for (int i = tid; i < TN * (FD / 4); i += 256) {
            int c  = i >> 5;
            int k4 = (i & 31) << 2;
            float4 v = *(const float4*)(xb + (size_t)(col0 + c) * FD + k4);
            float inv = ib[col0 + c];
            Bld[(k4 + 0) * TN + c] = v.x * inv;
            Bld[(k4 + 1) * TN + c] = v.y * inv;
            Bld[(k4 + 2) * TN + c] = v.z * inv;
            Bld[(k4 + 3) * TN + c] = v.w * inv;
        }
        __syncthreads();

        float acc[4][4];
        #pragma unroll
        for (int i = 0; i < 4; ++i)
            #pragma unroll
            for (int j = 0; j < 4; ++j) acc[i][j] = 0.f;

        for (int k = 0; k < FD; ++k) {
            float4 av = *(const float4*)(Ald + k * TM + (ty << 2));
            float4 bv = *(const float4*)(Bld + k * TN + (tx << 2));
            float a[4]  = {av.x, av.y, av.z, av.w};
            float bb[4] = {bv.x, bv.y, bv.z, bv.w};
            #pragma unroll
            for (int i = 0; i < 4; ++i)
                #pragma unroll
                for (int j = 0; j < 4; ++j)
                    acc[i][j] = fmaf(a[i], bb[j], acc[i][j]);
        }

        #pragma unroll
        for (int i = 0; i < 4; ++i) {
            int m = row0 + (ty << 2) + i;
            #pragma unroll
            for (int j = 0; j < 4; ++j) {
                int n = col0 + (tx << 2) + j;
                if (n != m) ins4(acc[i][j], n, tv[i], ti[i]);  // exclude diagonal
            }
        }
    }

    // ---- merge per-thread top-4 -> per-row top-4 (reuse B region) ----
    __syncthreads();
    float* mval = (float*)(smem + 32768);   // [64 rows][16 tx][4]
    int*   midx = (int*)(smem + 49152);
    #pragma unroll
    for (int i = 0; i < 4; ++i) {
        int r = (ty << 2) + i;
        #pragma unroll
        for (int s = 0; s < 4; ++s) {
            mval[(r * 16 + tx) * 4 + s] = tv[i][s];
            midx[(r * 16 + tx) * 4 + s] = ti[i][s];
        }
    }
    __syncthreads();

    double* fval = (double*)smem;          // 256 doubles = 2 KB (reuse A region)
    int*    fidx = (int*)(smem + 2048);    // 256 ints
    if (tid < TM) {
        int r = tid;
        float bv[4] = {NEG, NEG, NEG, NEG};
        int   bi[4] = {-1, -1, -1, -1};
        for (int t = 0; t < 16; ++t)
            #pragma unroll
            for (int s = 0; s < 4; ++s)
                ins4(mval[(r * 16 + t) * 4 + s], midx[(r * 16 + t) * 4 + s], bv, bi);
        #pragma unroll
        for (int s = 0; s < 4; ++s) fidx[r * 4 + s] = bi[s];
    }
    __syncthreads();

    // ---- fp64 refinement: one candidate per thread ----
    {
        int r = tid >> 2;
        int n = fidx[tid];
        int m = row0 + r;
        const float* pm = xb + (size_t)m * FD;
        const float* pn = xb + (size_t)n * FD;
        double acc = 0.0;
        for (int k = 0; k < FD; ++k)
            acc = fma((double)pm[k], (double)pn[k], acc);
        fval[tid] = acc / (nb[m] * nb[n]);
    }
    __syncthreads();

    // ---- exact top-2 select + symmetric scatter ----
    if (tid < TM) {
        int m = row0 + tid;
        const double* fv = fval + tid * 4;
        const int*    fi = fidx + tid * 4;
        int c1 = 0;
        for (int c = 1; c < 4; ++c)
            if (fv[c] > fv[c1] || (fv[c] == fv[c1] && fi[c] < fi[c1])) c1 = c;
        int c2 = -1;
        for (int c = 0; c < 4; ++c) {
            if (c == c1) continue;
            if (c2 < 0 || fv[c] > fv[c2] || (fv[c] == fv[c2] && fi[c] < fi[c2])) c2 = c;
        }
        double v1 = fv[c1]; int i1 = fi[c1];
        double v2 = fv[c2]; int i2 = fi[c2];
        size_t base = (size_t)b * Mdim * Mdim;

        // top_k includes the zeroed diagonal as a candidate with value 0:
        // val1 is always scattered; val2 only if it beats the diagonal zero.
        float h1 = (float)(0.5 * v1);
        atomicAdd(out + base + (size_t)m * Mdim + i1, h1);
        atomicAdd(out + base + (size_t)i1 * Mdim + m, h1);
        if (v2 > 0.0) {
            float h2 = (float)(0.5 * v2);
            atomicAdd(out + base + (size_t)m * Mdim + i2, h2);
            atomicAdd(out + base + (size_t)i2 * Mdim + m, h2);
        }
    }
}

extern "C" void kernel_launch(void* const* d_in, const int* in_sizes, int n_in,
                              void* d_out, int out_size, void* d_ws, size_t ws_size,
                              hipStream_t stream) {
    const float* x = (const float*)d_in[0];
    float* out = (float*)d_out;
    int Bn = in_sizes[0] / (Mdim * FD);   // 16

    double* nrm_d = (double*)d_ws;                                  // B*M doubles
    float*  inv_f = (float*)((char*)d_ws + (size_t)Bn * Mdim * 8);  // B*M floats

    // output is poisoned before every call: zero it (capture-legal)
    hipMemsetAsync(d_out, 0, (size_t)out_size * sizeof(float), stream);

    norms_kernel<<<Bn * Mdim, 64, 0, stream>>>(x, nrm_d, inv_f);
    topk_kernel<<<Bn * (Mdim / TM), 256, 0, stream>>>(x, nrm_d, inv_f, out);
}

// Round 2
// 412.997 us; speedup vs baseline: 1.8730x; 1.8730x over previous
//
#include <hip/hip_runtime.h>
#include <hip/hip_bf16.h>
#include <math.h>

#define Mdim 2048
#define FD   128
#define NEG  (-1e30f)
#define BSTRIDE 136   // bf16 elems per LDS B row: 128 + 8 pad (272 B = 17*16)

typedef __attribute__((ext_vector_type(8))) short short8;
typedef __attribute__((ext_vector_type(4))) float f32x4;

// ---------- Kernel 1: fp64 row norms + normalized bf16 copy ----------
__global__ void prep_kernel(const float* __restrict__ x,
                            double* __restrict__ nrm_d,
                            unsigned short* __restrict__ xnb) {
    int row = blockIdx.x * 4 + (threadIdx.x >> 6);   // one wave per row
    int lane = threadIdx.x & 63;
    const float* p = x + (size_t)row * FD;
    float v0 = p[lane], v1 = p[lane + 64];
    double d = (double)v0 * (double)v0 + (double)v1 * (double)v1;
    #pragma unroll
    for (int off = 32; off; off >>= 1) d += __shfl_down(d, off);
    d = __shfl(d, 0);
    double nrm = fmax(sqrt(d), 1e-12);
    if (lane == 0) nrm_d[row] = nrm;
    double inv = 1.0 / nrm;
    float a = (float)((double)v0 * inv);
    float b = (float)((double)v1 * inv);
    __hip_bfloat16 ha = __float2bfloat16(a);
    __hip_bfloat16 hb = __float2bfloat16(b);
    unsigned short* q = xnb + (size_t)row * FD;
    q[lane]      = *reinterpret_cast<unsigned short*>(&ha);
    q[lane + 64] = *reinterpret_cast<unsigned short*>(&hb);
}

// sorted-desc top-8 insert with early-out (fully unrolled, regs only)
__device__ __forceinline__ void ins8(float v, int n, float bv[8], int bi[8]) {
    if (v <= bv[7]) return;
    #pragma unroll
    for (int s = 0; s < 8; ++s) {
        if (v > bv[s]) {
            float ov = bv[s]; int oi = bi[s];
            bv[s] = v; bi[s] = n;
            v = ov; n = oi;
        }
    }
}

// ---------- Kernel 2: bf16 MFMA GEMM + top-k + fp64 refine + scatter ----------
__launch_bounds__(256, 2)
__global__ void topk_kernel(const float* __restrict__ x,
                            const unsigned short* __restrict__ xnb,
                            const double* __restrict__ nrm_d,
                            float* __restrict__ out) {
    // LDS: B chunk [128 cols][BSTRIDE] bf16 = 34816 B; +6 KB for refine buffers
    __shared__ __align__(16) char smem[34816 + 6144];
    unsigned short* Bld = (unsigned short*)smem;

    int b  = blockIdx.x >> 5;          // batch
    int rt = blockIdx.x & 31;          // row tile (64 rows)
    int row0 = rt * 64;
    const unsigned short* xb = xnb + (size_t)b * Mdim * FD;

    int tid  = threadIdx.x;
    int lane = tid & 63;
    int w    = tid >> 6;               // wave 0..3
    int wy   = w >> 1, wx = w & 1;     // 2x2 wave grid
    int c    = lane & 15, q = lane >> 4;

    // A fragments in registers for entire kernel: 2 row-subtiles x 4 k-steps
    // layout: lane holds A[m = c][k = q*8 + j]
    short8 afr[2][4];
    #pragma unroll
    for (int rs = 0; rs < 2; ++rs)
        #pragma unroll
        for (int s = 0; s < 4; ++s)
            afr[rs][s] = *(const short8*)(xb + (size_t)(row0 + wy*32 + rs*16 + c) * FD + s*32 + q*8);

    // per-lane top-2 per owned row: rows indexed by (rs, i) -> m = row0+wy*32+rs*16+q*4+i
    float tv[2][4][2]; int ti[2][4][2];
    #pragma unroll
    for (int rs = 0; rs < 2; ++rs)
        #pragma unroll
        for (int i = 0; i < 4; ++i) {
            tv[rs][i][0] = NEG; tv[rs][i][1] = NEG;
            ti[rs][i][0] = -1;  ti[rs][i][1] = -1;
        }

    for (int ch = 0; ch < Mdim / 128; ++ch) {
        int col0 = ch * 128;
        __syncthreads();
        // stage 128 cols x 128 k bf16 -> LDS (padded). 256 thr x 128 B each.
        {
            int r    = tid >> 1;
            int half = tid & 1;
            const short8* src = (const short8*)(xb + (size_t)(col0 + r) * FD + half*64);
            unsigned short* dst = Bld + r * BSTRIDE + half*64;
            #pragma unroll
            for (int i = 0; i < 8; ++i)
                *(short8*)(dst + i*8) = src[i];
        }
        __syncthreads();

        f32x4 acc[2][4];
        #pragma unroll
        for (int rs = 0; rs < 2; ++rs)
            #pragma unroll
            for (int ct = 0; ct < 4; ++ct)
                acc[rs][ct] = (f32x4){0.f, 0.f, 0.f, 0.f};

        #pragma unroll
        for (int s = 0; s < 4; ++s) {
            #pragma unroll
            for (int ct = 0; ct < 4; ++ct) {
                // B fragment: lane holds B[n = c][k = q*8+j] of tile (wx,ct)
                short8 bfr = *(const short8*)(Bld + (size_t)(wx*64 + ct*16 + c) * BSTRIDE + s*32 + q*8);
                acc[0][ct] = __builtin_amdgcn_mfma_f32_16x16x32_bf16(afr[0][s], bfr, acc[0][ct], 0, 0, 0);
                acc[1][ct] = __builtin_amdgcn_mfma_f32_16x16x32_bf16(afr[1][s], bfr, acc[1][ct], 0, 0, 0);
            }
        }

        // scan: C layout col = c, row = q*4 + reg
        #pragma unroll
        for (int rs = 0; rs < 2; ++rs) {
            #pragma unroll
            for (int i = 0; i < 4; ++i) {
                int m = row0 + wy*32 + rs*16 + q*4 + i;
                #pragma unroll
                for (int ct = 0; ct < 4; ++ct) {
                    int n = col0 + wx*64 + ct*16 + c;
                    float v = acc[rs][ct][i];
                    if (n != m && v > tv[rs][i][1]) {
                        if (v > tv[rs][i][0]) {
                            tv[rs][i][1] = tv[rs][i][0]; ti[rs][i][1] = ti[rs][i][0];
                            tv[rs][i][0] = v;            ti[rs][i][0] = n;
                        } else {
                            tv[rs][i][1] = v; ti[rs][i][1] = n;
                        }
                    }
                }
            }
        }
    }

    // ---- merge per-lane top-2 -> per-row candidate list (64 per row) ----
    __syncthreads();
    float* mval = (float*)smem;                 // [64 rows][32 slots][2]
    int*   midx = (int*)(smem + 16384);
    #pragma unroll
    for (int rs = 0; rs < 2; ++rs)
        #pragma unroll
        for (int i = 0; i < 4; ++i) {
            int rloc = wy*32 + rs*16 + q*4 + i;
            int slot = wx*16 + c;
            mval[(rloc*32 + slot)*2 + 0] = tv[rs][i][0];
            mval[(rloc*32 + slot)*2 + 1] = tv[rs][i][1];
            midx[(rloc*32 + slot)*2 + 0] = ti[rs][i][0];
            midx[(rloc*32 + slot)*2 + 1] = ti[rs][i][1];
        }
    __syncthreads();

    double* fval = (double*)(smem + 34816);     // [64][8]
    int*    fidx = (int*)(smem + 34816 + 4096); // [64][8]
    if (tid < 64) {
        float bv[8]; int bi[8];
        #pragma unroll
        for (int s = 0; s < 8; ++s) { bv[s] = NEG; bi[s] = -1; }
        for (int t2 = 0; t2 < 64; ++t2)
            ins8(mval[tid*64 + t2], midx[tid*64 + t2], bv, bi);
        #pragma unroll
        for (int s = 0; s < 8; ++s) fidx[tid*8 + s] = bi[s];
    }
    __syncthreads();

    // ---- fp64 refinement: 512 candidates, 2 per thread ----
    const float*  xf = x + (size_t)b * Mdim * FD;
    const double* nb = nrm_d + (size_t)b * Mdim;
    #pragma unroll
    for (int it = 0; it < 2; ++it) {
        int id = tid + it * 256;
        int r = id >> 3;
        int n = fidx[id];
        int m = row0 + r;
        const f32x4* pm = (const f32x4*)(xf + (size_t)m * FD);
        const f32x4* pn = (const f32x4*)(xf + (size_t)n * FD);
        double a0 = 0.0, a1 = 0.0;
        #pragma unroll 4
        for (int k4 = 0; k4 < FD/4; k4 += 2) {
            f32x4 u0 = pm[k4],   v0 = pn[k4];
            f32x4 u1 = pm[k4+1], v1 = pn[k4+1];
            a0 = fma((double)u0[0], (double)v0[0], a0);
            a0 = fma((double)u0[1], (double)v0[1], a0);
            a0 = fma((double)u0[2], (double)v0[2], a0);
            a0 = fma((double)u0[3], (double)v0[3], a0);
            a1 = fma((double)u1[0], (double)v1[0], a1);
            a1 = fma((double)u1[1], (double)v1[1], a1);
            a1 = fma((double)u1[2], (double)v1[2], a1);
            a1 = fma((double)u1[3], (double)v1[3], a1);
        }
        fval[id] = (a0 + a1) / (nb[m] * nb[n]);
    }
    __syncthreads();

    // ---- exact top-2 of refined 8 + symmetric scatter ----
    if (tid < 64) {
        int m = row0 + tid;
        const double* fv = fval + tid*8;
        const int*    fi = fidx + tid*8;
        int c1 = 0;
        for (int cc = 1; cc < 8; ++cc)
            if (fv[cc] > fv[c1] || (fv[cc] == fv[c1] && fi[cc] < fi[c1])) c1 = cc;
        int c2 = -1;
        for (int cc = 0; cc < 8; ++cc) {
            if (cc == c1) continue;
            if (c2 < 0 || fv[cc] > fv[c2] || (fv[cc] == fv[c2] && fi[cc] < fi[c2])) c2 = cc;
        }
        double v1 = fv[c1]; int i1 = fi[c1];
        double v2 = fv[c2]; int i2 = fi[c2];
        size_t base = (size_t)b * Mdim * Mdim;
        // reference top_k competes against the zeroed diagonal (value 0):
        // val1 always scatters; val2 only if it beats the diagonal zero.
        float h1 = (float)(0.5 * v1);
        atomicAdd(out + base + (size_t)m * Mdim + i1, h1);
        atomicAdd(out + base + (size_t)i1 * Mdim + m, h1);
        if (v2 > 0.0) {
            float h2 = (float)(0.5 * v2);
            atomicAdd(out + base + (size_t)m * Mdim + i2, h2);
            atomicAdd(out + base + (size_t)i2 * Mdim + m, h2);
        }
    }
}

extern "C" void kernel_launch(void* const* d_in, const int* in_sizes, int n_in,
                              void* d_out, int out_size, void* d_ws, size_t ws_size,
                              hipStream_t stream) {
    const float* x = (const float*)d_in[0];
    float* out = (float*)d_out;
    int Bn = in_sizes[0] / (Mdim * FD);   // 16

    double*         nrm_d = (double*)d_ws;                         // 32768 * 8 = 256 KB
    unsigned short* xnb   = (unsigned short*)((char*)d_ws + 262144); // 8 MB bf16 normalized

    hipMemsetAsync(d_out, 0, (size_t)out_size * sizeof(float), stream);

    prep_kernel<<<Bn * Mdim / 4, 256, 0, stream>>>(x, nrm_d, xnb);
    topk_kernel<<<Bn * 32, 256, 0, stream>>>(x, xnb, nrm_d, out);
}